// Round 9
// baseline (892.067 us; speedup 1.0000x reference)
//
#include <hip/hip_runtime.h>

typedef unsigned short u16;
typedef __attribute__((ext_vector_type(8))) short bf16x8;   // 8 bf16 (4 VGPRs)
typedef __attribute__((ext_vector_type(4))) float f32x4;
typedef __attribute__((ext_vector_type(2))) __fp16 h16x2;   // f16 pair (1 VGPR);
// NOTE: must be __fp16 (not _Float16) — clang's cvt_pkrtz/fdot2 builtins use
// the __fp16-based vector type and the two are not implicitly convertible.

#define D_EMB 1024
#define NBAT  256
#define AS1 __attribute__((address_space(1)))
#define AS3 __attribute__((address_space(3)))

__device__ __forceinline__ u16 f2bf(float f){
    unsigned int u = __float_as_uint(f);
    unsigned int r = (u + 0x7fffu + ((u >> 16) & 1u)) >> 16;  // RNE
    return (u16)r;
}
__device__ __forceinline__ float leaky(float x){ return x > 0.f ? x : 0.1f * x; }

// v_dot2_f32_f16: D = a.h0*b.h0 + a.h1*b.h1 + c (f16 mul, f32 accumulate).
// R8 compiled+passed with the builtin -> the instruction exists on gfx950.
__device__ __forceinline__ float dot2h(h16x2 a, h16x2 b, float c){
#if __has_builtin(__builtin_amdgcn_fdot2)
    return __builtin_amdgcn_fdot2(a, b, c, false);
#else
    return fmaf((float)a[0], (float)b[0], fmaf((float)a[1], (float)b[1], c));
#endif
}

// ---------------------------------------------------------------------------
// Pack img_emb(+pool_img as row 36) and cap_emb(+pool_txt as row 40) to bf16,
// and (for pool rows) also emit the pool-vector L2 norm (norm_kernel folded).
// imgw: [256][37][1024] bf16, capw: [256][41][1024] bf16
// ---------------------------------------------------------------------------
__global__ void pack_kernel(const float* __restrict__ pool_img, const float* __restrict__ img_emb,
                            const float* __restrict__ pool_txt, const float* __restrict__ cap_emb,
                            u16* __restrict__ imgw, u16* __restrict__ capw,
                            float* __restrict__ w1i, float* __restrict__ w1t){
    __shared__ float red[256];
    int row = blockIdx.x;            // 0..19967
    const float* src; u16* dst;
    bool is_pool; float* wout;
    if (row < NBAT * 37){
        int e = row / 37, rr = row - e * 37;
        is_pool = (rr == 36);
        src = (rr < 36) ? (img_emb + ((size_t)e * 36 + rr) * D_EMB) : (pool_img + (size_t)e * D_EMB);
        dst = imgw + (size_t)row * D_EMB;
        wout = w1i + e;
    } else {
        int r2 = row - NBAT * 37;
        int e = r2 / 41, rr = r2 - e * 41;
        is_pool = (rr == 40);
        src = (rr < 40) ? (cap_emb + ((size_t)e * 40 + rr) * D_EMB) : (pool_txt + (size_t)e * D_EMB);
        dst = capw + (size_t)r2 * D_EMB;
        wout = w1t + e;
    }
    int t = threadIdx.x;             // 256 threads, 4 floats each
    float4 v = ((const float4*)src)[t];
    unsigned long long pk = (unsigned long long)f2bf(v.x)
        | ((unsigned long long)f2bf(v.y) << 16)
        | ((unsigned long long)f2bf(v.z) << 32)
        | ((unsigned long long)f2bf(v.w) << 48);
    *(unsigned long long*)(dst + (size_t)t * 4) = pk;
    if (is_pool){                    // block-uniform branch
        red[t] = v.x*v.x + v.y*v.y + v.z*v.z + v.w*v.w;
        __syncthreads();
        for (int off = 128; off > 0; off >>= 1){
            if (t < off) red[t] += red[t + off];
            __syncthreads();
        }
        if (t == 0) *wout = sqrtf(red[0]);
    }
}

// ---------------------------------------------------------------------------
// MFMA Gram kernel: blk<256 -> G[b]=E_img E_img^T (R=36), else H[b] (R=40).
// Output written DIRECTLY as f16 pairs (ghpack kernel + fp32 roundtrip
// deleted). Lane (frow=col, q) holds C[rbase+g][col]; by symmetry the pair
// (C[r0][col], C[r0+1][col]) IS row col's pair (G[col][r0], G[col][r0+1])
// -> pack with cvt_pkrtz, store at Ghout[col*NP + r0/2]. Exact: C[r][c] and
// C[c][r] come from identical MFMA accumulation order.
// ---------------------------------------------------------------------------
__launch_bounds__(256, 2)
__global__ void gram_kernel(const u16* __restrict__ imgw, const u16* __restrict__ capw,
                            h16x2* __restrict__ Gh, h16x2* __restrict__ Hh){
    __shared__ __align__(16) char gsm[6144];    // 3 tiles x 2 kk x 64 lanes x 16B
    int blk = blockIdx.x;
    int tid = threadIdx.x, lane = tid & 63;
    int wave = __builtin_amdgcn_readfirstlane(tid >> 6);
    int frow = lane & 15, q = lane >> 4;

    const u16* E; h16x2* Ghout; int R, NP;
    if (blk < NBAT){ E = imgw + (size_t)blk * 37 * D_EMB; Ghout = Gh + (size_t)blk * 648; R = 36; NP = 18; }
    else { int b = blk - NBAT; E = capw + (size_t)b * 41 * D_EMB; Ghout = Hh + (size_t)b * 800; R = 40; NP = 20; }

    {   // zero staging once (pad rows stay zero)
        uint4 z = {0u,0u,0u,0u};
        for (int off = tid * 16; off < 6144; off += 4096) *(uint4*)(gsm + off) = z;
    }

    // staging groups g = kk*3 + t, g in [0,6)
    const u16* gsrc[2]; int goff[2]; bool gval[2];
    #pragma unroll
    for (int j = 0; j < 2; ++j){
        int g = wave + j * 4;
        gval[j] = false; gsrc[j] = E; goff[j] = 0;
        if (g < 6){
            int kk = g / 3, t = g - kk * 3;
            int row = t * 16 + frow;
            gsrc[j] = E + (size_t)row * D_EMB + kk * 32 + q * 8;
            goff[j] = g * 1024;
            gval[j] = (row < R);
        }
    }

    int wm = wave >> 1, wn = wave & 1;
    int nTm = wm ? 1 : 2, nTn = wn ? 1 : 2;
    f32x4 acc[2][2];
    #pragma unroll
    for (int a = 0; a < 2; ++a)
        #pragma unroll
        for (int b = 0; b < 2; ++b) acc[a][b] = (f32x4){0.f,0.f,0.f,0.f};

    for (int c = 0; c < 16; ++c){
        __syncthreads();
        #pragma unroll
        for (int j = 0; j < 2; ++j){
            if (gval[j]){
                __builtin_amdgcn_global_load_lds(
                    (const AS1 void*)(const void*)(gsrc[j] + c * 64),
                    (AS3 void*)(void*)(gsm + goff[j] + lane * 16),
                    16, 0, 0);
            }
        }
        __syncthreads();
        #pragma unroll
        for (int kk = 0; kk < 2; ++kk){
            bf16x8 fA[2], fB[2];
            #pragma unroll
            for (int mi = 0; mi < 2; ++mi)
                if (mi < nTm) fA[mi] = *(const bf16x8*)(gsm + ((kk * 3 + (wm + mi * 2)) * 64 + lane) * 16);
            #pragma unroll
            for (int ni = 0; ni < 2; ++ni)
                if (ni < nTn) fB[ni] = *(const bf16x8*)(gsm + ((kk * 3 + (wn + ni * 2)) * 64 + lane) * 16);
            #pragma unroll
            for (int mi = 0; mi < 2; ++mi)
                if (mi < nTm)
                    #pragma unroll
                    for (int ni = 0; ni < 2; ++ni)
                        if (ni < nTn)
                            acc[mi][ni] = __builtin_amdgcn_mfma_f32_16x16x32_bf16(
                                fA[mi], fB[ni], acc[mi][ni], 0, 0, 0);
        }
    }

    #pragma unroll
    for (int mi = 0; mi < 2; ++mi){
        if (mi < nTm){
            int tm = wm + mi * 2;
            #pragma unroll
            for (int ni = 0; ni < 2; ++ni){
                if (ni < nTn){
                    int tn = wn + ni * 2;
                    int col = tn * 16 + frow;
                    int rbase = tm * 16 + q * 4;
                    if (col < R){
                        #pragma unroll
                        for (int gg = 0; gg < 4; gg += 2){
                            int r0 = rbase + gg;
                            if (r0 + 1 < R)   // R even: pairs never straddle
                                Ghout[col * NP + (r0 >> 1)] =
                                    __builtin_amdgcn_cvt_pkrtz(acc[mi][ni][gg], acc[mi][ni][gg + 1]);
                        }
                    }
                }
            }
        }
    }
}

// ---------------------------------------------------------------------------
// Fused main kernel. One block = 2 images x 2 captions.
// GEMM phase: R0 structure (best evidence). bounds (256,6): 6 blocks/CU --
// 40 arch + 36 AGPR = 76 <= 80 unified at 6 waves/EU; LDS 6x26624 = 156 KB
// <= 160 KB. R1/R8 showed time tracks occupancy (latency-bound kernel).
// Post phase: triangle dot2 quadratic forms (zz = sum u_r(G_rr u_r +
// 2 sum_{k>r} G_rk u_k), pair-aligned) -- 306/380 dot2 vs R8's 648/800,
// and half the Gh/Hh load traffic. Dual accumulators (w0/w1) halve the
// per-row serial dot2 dependency chain (R8 diagnosis: latency-bound, not
// VALU-throughput-bound).
// ---------------------------------------------------------------------------
__launch_bounds__(256, 6)
__global__ void fused_kernel(const u16* __restrict__ imgw, const u16* __restrict__ capw,
                             const h16x2* __restrict__ Gh, const h16x2* __restrict__ Hh,
                             const float* __restrict__ w1i, const float* __restrict__ w1t,
                             float* __restrict__ out){
    __shared__ __align__(16) char smem[26624];
    float* Call = (float*)smem;                 // overlay after GEMM: [74][85]
    float* rnb  = (float*)(smem + 25160);       // [4][36]
    float* cnb  = (float*)(smem + 25736);       // [4][40]

    int tid  = threadIdx.x;
    int lane = tid & 63;
    int wave = __builtin_amdgcn_readfirstlane(tid >> 6);
    int frow = lane & 15, q = lane >> 4;

    int lin = blockIdx.x;
    int xcd = lin & 7;                   // XCD-aware swizzle (16384 % 8 == 0, bijective)
    int s   = lin >> 3;                  // 0..2047
    int b_t = (xcd << 4) | (s & 15);     // each XCD owns 16 b-tiles
    int i_t = s >> 4;                    // 0..127
    int b0 = b_t * 2, i0 = i_t * 2;
    const u16* Ag = imgw + (size_t)b0 * 37 * D_EMB;   // 74 rows
    const u16* Bg = capw + (size_t)i0 * 41 * D_EMB;   // 82 rows

    {   // zero staging region once (pad slots stay zero forever)
        uint4 z = {0u,0u,0u,0u};
        for (int off = tid * 16; off < 22528; off += 4096) *(uint4*)(smem + off) = z;
    }

    // staging groups: A g in [0,10): tm=g%5, kk=g/5, off g*1024
    //                 B g in [10,22): gb=g-10, tn=gb%6, kk=gb/6, off 10240+gb*1024
    const u16* gsrc[6]; int goff[6]; bool gval[6];
    #pragma unroll
    for (int j = 0; j < 6; ++j){
        int g = wave + j * 4;
        gval[j] = false; gsrc[j] = Ag; goff[j] = 0;
        if (g < 22){
            if (g < 10){
                int tm = g % 5, kk = g / 5;
                int row = tm * 16 + frow;
                gsrc[j] = Ag + (size_t)row * D_EMB + kk * 32 + q * 8;
                goff[j] = g * 1024;
                gval[j] = (row < 74);
            } else {
                int gb = g - 10;
                int tn = gb % 6, kk = gb / 6;
                int row = tn * 16 + frow;
                gsrc[j] = Bg + (size_t)row * D_EMB + kk * 32 + q * 8;
                goff[j] = 10240 + gb * 1024;
                gval[j] = (row < 82);
            }
        }
    }

    int wm = wave >> 1, wn = wave & 1;     // 2x2 wave grid over 5x6 MFMA tiles
    int nTm = wm ? 2 : 3;                  // m-tiles {wm, wm+2, wm+4} < 5
    f32x4 acc[3][3];
    #pragma unroll
    for (int aa = 0; aa < 3; ++aa)
        #pragma unroll
        for (int bb = 0; bb < 3; ++bb) acc[aa][bb] = (f32x4){0.f, 0.f, 0.f, 0.f};

    for (int c = 0; c < 16; ++c){          // K chunks of 64
        __syncthreads();                   // prev chunk's frag reads done
        #pragma unroll
        for (int j = 0; j < 6; ++j){
            if (gval[j]){
                __builtin_amdgcn_global_load_lds(
                    (const AS1 void*)(const void*)(gsrc[j] + c * 64),
                    (AS3 void*)(void*)(smem + goff[j] + lane * 16),
                    16, 0, 0);
            }
        }
        __syncthreads();                   // drains vmcnt -> data in LDS
        #pragma unroll
        for (int kk = 0; kk < 2; ++kk){
            bf16x8 bfr[3];
            #pragma unroll
            for (int ni = 0; ni < 3; ++ni){
                int tn = wn + ni * 2;
                bfr[ni] = *(const bf16x8*)(smem + 10240 + ((kk * 6 + tn) * 64 + lane) * 16);
            }
            #pragma unroll
            for (int mi = 0; mi < 3; ++mi){
                if (mi < nTm){
                    int tm = wm + mi * 2;
                    bf16x8 af = *(const bf16x8*)(smem + ((kk * 5 + tm) * 64 + lane) * 16);
                    #pragma unroll
                    for (int ni = 0; ni < 3; ++ni){
                        acc[mi][ni] = __builtin_amdgcn_mfma_f32_16x16x32_bf16(
                            af, bfr[ni], acc[mi][ni], 0, 0, 0);
                    }
                }
            }
        }
    }
    __syncthreads();                       // all frag reads done before overlay

    // C/D layout: col = lane&15 (B-row), row = (lane>>4)*4 + reg (A-row)
    #pragma unroll
    for (int mi = 0; mi < 3; ++mi){
        if (mi < nTm){
            int tm = wm + mi * 2;
            #pragma unroll
            for (int ni = 0; ni < 3; ++ni){
                int tn = wn + ni * 2;
                int col = tn * 16 + frow;
                int rbase = tm * 16 + q * 4;
                if (col < 82){
                    #pragma unroll
                    for (int g = 0; g < 4; ++g){
                        int rowc = rbase + g;
                        if (rowc < 74) Call[rowc * 85 + col] = acc[mi][ni][g];
                    }
                }
            }
        }
    }
    __syncthreads();

    // ----- post-processing: one wave per (b,i) pair -----
    int pb = wave >> 1, pi = wave & 1;
    int bg = b0 + pb, ig = i0 + pi;
    const float* Sv = Call + (pb * 37) * 85 + pi * 41;  // S[r*85+l]; p[r]=S[r*85+40]; qv[l]=S[36*85+l]
    const h16x2* Gp = Gh + (size_t)bg * 648;            // wave-uniform base
    const h16x2* Hp = Hh + (size_t)ig * 800;

    {   // row norms over words (lanes = regions); 9x softmax scale folded in
        int r0 = (lane < 36) ? lane : 35;
        float s2 = 0.f;
        #pragma unroll
        for (int l = 0; l < 40; ++l){ float x = leaky(Sv[r0 * 85 + l]); s2 = fmaf(x, x, s2); }
        if (lane < 36) rnb[wave * 36 + lane] = 9.f / (sqrtf(s2) + 1e-8f);
    }
    float t2i_sum;
    {   // lanes = words; u packed as 18 f16 pairs (cvt_pkrtz), dd cancels
        int lc = (lane < 40) ? lane : 39;
        h16x2 uh[18];
        float num = 0.f;
        #pragma unroll
        for (int r = 0; r < 36; r += 2){
            float e0 = __expf(leaky(Sv[r * 85 + lc] * rnb[wave * 36 + r]));
            float e1 = __expf(leaky(Sv[(r + 1) * 85 + lc] * rnb[wave * 36 + r + 1]));
            num = fmaf(e0, Sv[r * 85 + 40], fmaf(e1, Sv[(r + 1) * 85 + 40], num));
            uh[r >> 1] = __builtin_amdgcn_cvt_pkrtz(e0, e1);
        }
        // zz = sum_r u_r * (G_rr u_r + 2 * sum_{k>r} G_rk u_k)  (triangle, pair-aligned)
        float zz = 0.f;
        #pragma unroll
        for (int rr = 0; rr < 36; ++rr){
            int t = rr >> 1;
            float w0 = 0.f, w1 = 0.f;                  // dual acc: halves chain depth
            #pragma unroll
            for (int j = t + 1; j < 18; ++j){
                if ((j - t) & 1) w0 = dot2h(uh[j], Gp[rr * 18 + j], w0);
                else             w1 = dot2h(uh[j], Gp[rr * 18 + j], w1);
            }
            h16x2 dp = Gp[rr * 18 + t];                // (G[rr][2t], G[rr][2t+1])
            float tail = w0 + w1;                      // sum over k >= 2t+2
            if ((rr & 1) == 0){                        // diag=dp[0]; dp[1]=G[rr][rr+1]
                float u0 = (float)uh[t][0], u1v = (float)uh[t][1];
                zz = fmaf(u0, fmaf((float)dp[0], u0, 2.f * fmaf((float)dp[1], u1v, tail)), zz);
            } else {                                   // diag=dp[1]; tail covers all k>rr
                float u1v = (float)uh[t][1];
                zz = fmaf(u1v, fmaf((float)dp[1], u1v, 2.f * tail), zz);
            }
        }
        float w2s = sqrtf(fmaxf(zz, 0.f));
        float sim = num / fmaxf(w1t[ig] * w2s, 1e-8f);   // dd cancels in ratio
        sim = (lane < 40) ? sim : 0.f;
        #pragma unroll
        for (int off = 32; off > 0; off >>= 1) sim += __shfl_down(sim, off);
        t2i_sum = sim;
    }

    {   // column norms over regions (lanes = words); 9x folded
        int l0 = (lane < 40) ? lane : 39;
        float s2 = 0.f;
        #pragma unroll
        for (int r = 0; r < 36; ++r){ float x = leaky(Sv[r * 85 + l0]); s2 = fmaf(x, x, s2); }
        if (lane < 40) cnb[wave * 40 + lane] = 9.f / (sqrtf(s2) + 1e-8f);
    }
    float i2t_sum;
    {   // lanes = regions; v packed as 20 f16 pairs
        int rc = (lane < 36) ? lane : 35;
        h16x2 vh[20];
        float num = 0.f;
        #pragma unroll
        for (int l = 0; l < 40; l += 2){
            float e0 = __expf(leaky(Sv[rc * 85 + l] * cnb[wave * 40 + l]));
            float e1 = __expf(leaky(Sv[rc * 85 + l + 1] * cnb[wave * 40 + l + 1]));
            num = fmaf(e0, Sv[36 * 85 + l], fmaf(e1, Sv[36 * 85 + l + 1], num));
            vh[l >> 1] = __builtin_amdgcn_cvt_pkrtz(e0, e1);
        }
        float zz = 0.f;
        #pragma unroll
        for (int ll = 0; ll < 40; ++ll){
            int t = ll >> 1;
            float w0 = 0.f, w1 = 0.f;
            #pragma unroll
            for (int j = t + 1; j < 20; ++j){
                if ((j - t) & 1) w0 = dot2h(vh[j], Hp[ll * 20 + j], w0);
                else             w1 = dot2h(vh[j], Hp[ll * 20 + j], w1);
            }
            h16x2 dp = Hp[ll * 20 + t];
            float tail = w0 + w1;
            if ((ll & 1) == 0){
                float v0 = (float)vh[t][0], v1 = (float)vh[t][1];
                zz = fmaf(v0, fmaf((float)dp[0], v0, 2.f * fmaf((float)dp[1], v1, tail)), zz);
            } else {
                float v1 = (float)vh[t][1];
                zz = fmaf(v1, fmaf((float)dp[1], v1, 2.f * tail), zz);
            }
        }
        float w2s = sqrtf(fmaxf(zz, 0.f));
        float sim = num / fmaxf(w1i[bg] * w2s, 1e-8f);
        sim = (lane < 36) ? sim : 0.f;
        #pragma unroll
        for (int off = 32; off > 0; off >>= 1) sim += __shfl_down(sim, off);
        i2t_sum = sim;
    }

    if (lane == 0)
        out[bg * 256 + ig] = t2i_sum * (1.f / 40.f) + i2t_sum * (1.f / 36.f) + Sv[36 * 85 + 40];
}

// ---------------------------------------------------------------------------
extern "C" void kernel_launch(void* const* d_in, const int* in_sizes, int n_in,
                              void* d_out, int out_size, void* d_ws, size_t ws_size,
                              hipStream_t stream){
    const float* pool_img = (const float*)d_in[0];
    const float* img_emb  = (const float*)d_in[1];
    const float* pool_txt = (const float*)d_in[2];
    const float* cap_emb  = (const float*)d_in[3];
    float* out = (float*)d_out;

    char* ws = (char*)d_ws;                         // needs ~43 MB
    size_t o = 0;
    u16* imgw = (u16*)(ws + o);  o += (size_t)256 * 37 * 1024 * 2;
    u16* capw = (u16*)(ws + o);  o += (size_t)256 * 41 * 1024 * 2;
    float* w1i = (float*)(ws + o); o += 1024;
    float* w1t = (float*)(ws + o); o += 1024;
    h16x2* Gh = (h16x2*)(ws + o); o += (size_t)256 * 648 * 4;   // G as f16 pairs
    h16x2* Hh = (h16x2*)(ws + o); o += (size_t)256 * 800 * 4;   // H as f16 pairs

    pack_kernel<<<19968, 256, 0, stream>>>(pool_img, img_emb, pool_txt, cap_emb,
                                           imgw, capw, w1i, w1t);
    gram_kernel<<<512, 256, 0, stream>>>(imgw, capw, Gh, Hh);
    fused_kernel<<<16384, 256, 0, stream>>>(imgw, capw, Gh, Hh, w1i, w1t, out);
}

// Round 10
// 717.531 us; speedup vs baseline: 1.2432x; 1.2432x over previous
//
#include <hip/hip_runtime.h>

typedef unsigned short u16;
typedef __attribute__((ext_vector_type(8))) short bf16x8;   // 8 bf16 (4 VGPRs)
typedef __attribute__((ext_vector_type(4))) float f32x4;
typedef __attribute__((ext_vector_type(2))) __fp16 h16x2;   // f16 pair (1 VGPR);
// NOTE: must be __fp16 (not _Float16) — clang's cvt_pkrtz/fdot2 builtins use
// the __fp16-based vector type and the two are not implicitly convertible.

#define D_EMB 1024
#define NBAT  256
#define AS1 __attribute__((address_space(1)))
#define AS3 __attribute__((address_space(3)))

__device__ __forceinline__ u16 f2bf(float f){
    unsigned int u = __float_as_uint(f);
    unsigned int r = (u + 0x7fffu + ((u >> 16) & 1u)) >> 16;  // RNE
    return (u16)r;
}
__device__ __forceinline__ float leaky(float x){ return x > 0.f ? x : 0.1f * x; }

// v_dot2_f32_f16: D = a.h0*b.h0 + a.h1*b.h1 + c (f16 mul, f32 accumulate).
__device__ __forceinline__ float dot2h(h16x2 a, h16x2 b, float c){
#if __has_builtin(__builtin_amdgcn_fdot2)
    return __builtin_amdgcn_fdot2(a, b, c, false);
#else
    return fmaf((float)a[0], (float)b[0], fmaf((float)a[1], (float)b[1], c));
#endif
}

// ---------------------------------------------------------------------------
// Pack img_emb(+pool_img as row 36) and cap_emb(+pool_txt as row 40) to bf16,
// and (for pool rows) also emit the pool-vector L2 norm (norm_kernel folded).
// imgw: [256][37][1024] bf16, capw: [256][41][1024] bf16
// ---------------------------------------------------------------------------
__global__ void pack_kernel(const float* __restrict__ pool_img, const float* __restrict__ img_emb,
                            const float* __restrict__ pool_txt, const float* __restrict__ cap_emb,
                            u16* __restrict__ imgw, u16* __restrict__ capw,
                            float* __restrict__ w1i, float* __restrict__ w1t){
    __shared__ float red[256];
    int row = blockIdx.x;            // 0..19967
    const float* src; u16* dst;
    bool is_pool; float* wout;
    if (row < NBAT * 37){
        int e = row / 37, rr = row - e * 37;
        is_pool = (rr == 36);
        src = (rr < 36) ? (img_emb + ((size_t)e * 36 + rr) * D_EMB) : (pool_img + (size_t)e * D_EMB);
        dst = imgw + (size_t)row * D_EMB;
        wout = w1i + e;
    } else {
        int r2 = row - NBAT * 37;
        int e = r2 / 41, rr = r2 - e * 41;
        is_pool = (rr == 40);
        src = (rr < 40) ? (cap_emb + ((size_t)e * 40 + rr) * D_EMB) : (pool_txt + (size_t)e * D_EMB);
        dst = capw + (size_t)r2 * D_EMB;
        wout = w1t + e;
    }
    int t = threadIdx.x;             // 256 threads, 4 floats each
    float4 v = ((const float4*)src)[t];
    unsigned long long pk = (unsigned long long)f2bf(v.x)
        | ((unsigned long long)f2bf(v.y) << 16)
        | ((unsigned long long)f2bf(v.z) << 32)
        | ((unsigned long long)f2bf(v.w) << 48);
    *(unsigned long long*)(dst + (size_t)t * 4) = pk;
    if (is_pool){                    // block-uniform branch
        red[t] = v.x*v.x + v.y*v.y + v.z*v.z + v.w*v.w;
        __syncthreads();
        for (int off = 128; off > 0; off >>= 1){
            if (t < off) red[t] += red[t + off];
            __syncthreads();
        }
        if (t == 0) *wout = sqrtf(red[0]);
    }
}

// ---------------------------------------------------------------------------
// MFMA Gram kernel: blk<256 -> G[b]=E_img E_img^T (R=36), else H[b] (R=40).
// Output written DIRECTLY as f16 pairs (validated in R9; deletes ghpack +
// fp32 roundtrip). Lane holds C[rbase+g][col]; by symmetry the pair
// (C[r0][col], C[r0+1][col]) IS row col's pair (G[col][r0], G[col][r0+1]).
// ---------------------------------------------------------------------------
__launch_bounds__(256, 2)
__global__ void gram_kernel(const u16* __restrict__ imgw, const u16* __restrict__ capw,
                            h16x2* __restrict__ Gh, h16x2* __restrict__ Hh){
    __shared__ __align__(16) char gsm[6144];    // 3 tiles x 2 kk x 64 lanes x 16B
    int blk = blockIdx.x;
    int tid = threadIdx.x, lane = tid & 63;
    int wave = __builtin_amdgcn_readfirstlane(tid >> 6);
    int frow = lane & 15, q = lane >> 4;

    const u16* E; h16x2* Ghout; int R, NP;
    if (blk < NBAT){ E = imgw + (size_t)blk * 37 * D_EMB; Ghout = Gh + (size_t)blk * 648; R = 36; NP = 18; }
    else { int b = blk - NBAT; E = capw + (size_t)b * 41 * D_EMB; Ghout = Hh + (size_t)b * 800; R = 40; NP = 20; }

    {   // zero staging once (pad rows stay zero)
        uint4 z = {0u,0u,0u,0u};
        for (int off = tid * 16; off < 6144; off += 4096) *(uint4*)(gsm + off) = z;
    }

    // staging groups g = kk*3 + t, g in [0,6)
    const u16* gsrc[2]; int goff[2]; bool gval[2];
    #pragma unroll
    for (int j = 0; j < 2; ++j){
        int g = wave + j * 4;
        gval[j] = false; gsrc[j] = E; goff[j] = 0;
        if (g < 6){
            int kk = g / 3, t = g - kk * 3;
            int row = t * 16 + frow;
            gsrc[j] = E + (size_t)row * D_EMB + kk * 32 + q * 8;
            goff[j] = g * 1024;
            gval[j] = (row < R);
        }
    }

    int wm = wave >> 1, wn = wave & 1;
    int nTm = wm ? 1 : 2, nTn = wn ? 1 : 2;
    f32x4 acc[2][2];
    #pragma unroll
    for (int a = 0; a < 2; ++a)
        #pragma unroll
        for (int b = 0; b < 2; ++b) acc[a][b] = (f32x4){0.f,0.f,0.f,0.f};

    for (int c = 0; c < 16; ++c){
        __syncthreads();
        #pragma unroll
        for (int j = 0; j < 2; ++j){
            if (gval[j]){
                __builtin_amdgcn_global_load_lds(
                    (const AS1 void*)(const void*)(gsrc[j] + c * 64),
                    (AS3 void*)(void*)(gsm + goff[j] + lane * 16),
                    16, 0, 0);
            }
        }
        __syncthreads();
        #pragma unroll
        for (int kk = 0; kk < 2; ++kk){
            bf16x8 fA[2], fB[2];
            #pragma unroll
            for (int mi = 0; mi < 2; ++mi)
                if (mi < nTm) fA[mi] = *(const bf16x8*)(gsm + ((kk * 3 + (wm + mi * 2)) * 64 + lane) * 16);
            #pragma unroll
            for (int ni = 0; ni < 2; ++ni)
                if (ni < nTn) fB[ni] = *(const bf16x8*)(gsm + ((kk * 3 + (wn + ni * 2)) * 64 + lane) * 16);
            #pragma unroll
            for (int mi = 0; mi < 2; ++mi)
                if (mi < nTm)
                    #pragma unroll
                    for (int ni = 0; ni < 2; ++ni)
                        if (ni < nTn)
                            acc[mi][ni] = __builtin_amdgcn_mfma_f32_16x16x32_bf16(
                                fA[mi], fB[ni], acc[mi][ni], 0, 0, 0);
        }
    }

    #pragma unroll
    for (int mi = 0; mi < 2; ++mi){
        if (mi < nTm){
            int tm = wm + mi * 2;
            #pragma unroll
            for (int ni = 0; ni < 2; ++ni){
                if (ni < nTn){
                    int tn = wn + ni * 2;
                    int col = tn * 16 + frow;
                    int rbase = tm * 16 + q * 4;
                    if (col < R){
                        #pragma unroll
                        for (int gg = 0; gg < 4; gg += 2){
                            int r0 = rbase + gg;
                            if (r0 + 1 < R)   // R even: pairs never straddle
                                Ghout[col * NP + (r0 >> 1)] =
                                    __builtin_amdgcn_cvt_pkrtz(acc[mi][ni][gg], acc[mi][ni][gg + 1]);
                        }
                    }
                }
            }
        }
    }
}

// ---------------------------------------------------------------------------
// Fused main kernel. One block = 2 images x 2 captions.
// EXACT R8 configuration (best verified: 722 total / ~695 fused):
// GEMM phase: R0 structure, K=64 chunks, 2 barriers/chunk, (256,5).
// Post phase: full-row dot2 quadratic forms (648/800 dot2) -- UNIFORM row
// structure so per-row Gp/Hp pairs batch into wide uniform loads. R9's
// triangle variant (47% fewer ops) REGRESSED 24%: ragged per-row loads
// fragmented the load batching + lengthened the zz dependency chain.
// Op-count is not the objective in a latency-bound phase; keep uniform rows.
// ---------------------------------------------------------------------------
__launch_bounds__(256, 5)
__global__ void fused_kernel(const u16* __restrict__ imgw, const u16* __restrict__ capw,
                             const h16x2* __restrict__ Gh, const h16x2* __restrict__ Hh,
                             const float* __restrict__ w1i, const float* __restrict__ w1t,
                             float* __restrict__ out){
    __shared__ __align__(16) char smem[26624];
    float* Call = (float*)smem;                 // overlay after GEMM: [74][85]
    float* rnb  = (float*)(smem + 25160);       // [4][36]
    float* cnb  = (float*)(smem + 25736);       // [4][40]

    int tid  = threadIdx.x;
    int lane = tid & 63;
    int wave = __builtin_amdgcn_readfirstlane(tid >> 6);
    int frow = lane & 15, q = lane >> 4;

    int lin = blockIdx.x;
    int xcd = lin & 7;                   // XCD-aware swizzle (16384 % 8 == 0, bijective)
    int s   = lin >> 3;                  // 0..2047
    int b_t = (xcd << 4) | (s & 15);     // each XCD owns 16 b-tiles
    int i_t = s >> 4;                    // 0..127
    int b0 = b_t * 2, i0 = i_t * 2;
    const u16* Ag = imgw + (size_t)b0 * 37 * D_EMB;   // 74 rows
    const u16* Bg = capw + (size_t)i0 * 41 * D_EMB;   // 82 rows

    {   // zero staging region once (pad slots stay zero forever)
        uint4 z = {0u,0u,0u,0u};
        for (int off = tid * 16; off < 22528; off += 4096) *(uint4*)(smem + off) = z;
    }

    // staging groups: A g in [0,10): tm=g%5, kk=g/5, off g*1024
    //                 B g in [10,22): gb=g-10, tn=gb%6, kk=gb/6, off 10240+gb*1024
    const u16* gsrc[6]; int goff[6]; bool gval[6];
    #pragma unroll
    for (int j = 0; j < 6; ++j){
        int g = wave + j * 4;
        gval[j] = false; gsrc[j] = Ag; goff[j] = 0;
        if (g < 22){
            if (g < 10){
                int tm = g % 5, kk = g / 5;
                int row = tm * 16 + frow;
                gsrc[j] = Ag + (size_t)row * D_EMB + kk * 32 + q * 8;
                goff[j] = g * 1024;
                gval[j] = (row < 74);
            } else {
                int gb = g - 10;
                int tn = gb % 6, kk = gb / 6;
                int row = tn * 16 + frow;
                gsrc[j] = Bg + (size_t)row * D_EMB + kk * 32 + q * 8;
                goff[j] = 10240 + gb * 1024;
                gval[j] = (row < 82);
            }
        }
    }

    int wm = wave >> 1, wn = wave & 1;     // 2x2 wave grid over 5x6 MFMA tiles
    int nTm = wm ? 2 : 3;                  // m-tiles {wm, wm+2, wm+4} < 5
    f32x4 acc[3][3];
    #pragma unroll
    for (int aa = 0; aa < 3; ++aa)
        #pragma unroll
        for (int bb = 0; bb < 3; ++bb) acc[aa][bb] = (f32x4){0.f, 0.f, 0.f, 0.f};

    for (int c = 0; c < 16; ++c){          // K chunks of 64
        __syncthreads();                   // prev chunk's frag reads done
        #pragma unroll
        for (int j = 0; j < 6; ++j){
            if (gval[j]){
                __builtin_amdgcn_global_load_lds(
                    (const AS1 void*)(const void*)(gsrc[j] + c * 64),
                    (AS3 void*)(void*)(smem + goff[j] + lane * 16),
                    16, 0, 0);
            }
        }
        __syncthreads();                   // drains vmcnt -> data in LDS
        #pragma unroll
        for (int kk = 0; kk < 2; ++kk){
            bf16x8 bfr[3];
            #pragma unroll
            for (int ni = 0; ni < 3; ++ni){
                int tn = wn + ni * 2;
                bfr[ni] = *(const bf16x8*)(smem + 10240 + ((kk * 6 + tn) * 64 + lane) * 16);
            }
            #pragma unroll
            for (int mi = 0; mi < 3; ++mi){
                if (mi < nTm){
                    int tm = wm + mi * 2;
                    bf16x8 af = *(const bf16x8*)(smem + ((kk * 5 + tm) * 64 + lane) * 16);
                    #pragma unroll
                    for (int ni = 0; ni < 3; ++ni){
                        acc[mi][ni] = __builtin_amdgcn_mfma_f32_16x16x32_bf16(
                            af, bfr[ni], acc[mi][ni], 0, 0, 0);
                    }
                }
            }
        }
    }
    __syncthreads();                       // all frag reads done before overlay

    // C/D layout: col = lane&15 (B-row), row = (lane>>4)*4 + reg (A-row)
    #pragma unroll
    for (int mi = 0; mi < 3; ++mi){
        if (mi < nTm){
            int tm = wm + mi * 2;
            #pragma unroll
            for (int ni = 0; ni < 3; ++ni){
                int tn = wn + ni * 2;
                int col = tn * 16 + frow;
                int rbase = tm * 16 + q * 4;
                if (col < 82){
                    #pragma unroll
                    for (int g = 0; g < 4; ++g){
                        int rowc = rbase + g;
                        if (rowc < 74) Call[rowc * 85 + col] = acc[mi][ni][g];
                    }
                }
            }
        }
    }
    __syncthreads();

    // ----- post-processing: one wave per (b,i) pair -----
    int pb = wave >> 1, pi = wave & 1;
    int bg = b0 + pb, ig = i0 + pi;
    const float* Sv = Call + (pb * 37) * 85 + pi * 41;  // S[r*85+l]; p[r]=S[r*85+40]; qv[l]=S[36*85+l]
    const h16x2* Gp = Gh + (size_t)bg * 648;            // wave-uniform base
    const h16x2* Hp = Hh + (size_t)ig * 800;

    {   // row norms over words (lanes = regions); 9x softmax scale folded in
        int r0 = (lane < 36) ? lane : 35;
        float s2 = 0.f;
        #pragma unroll
        for (int l = 0; l < 40; ++l){ float x = leaky(Sv[r0 * 85 + l]); s2 = fmaf(x, x, s2); }
        if (lane < 36) rnb[wave * 36 + lane] = 9.f / (sqrtf(s2) + 1e-8f);
    }
    float t2i_sum;
    {   // lanes = words; u packed as 18 f16 pairs (cvt_pkrtz), dd cancels
        int lc = (lane < 40) ? lane : 39;
        h16x2 uh[18];
        float num = 0.f;
        #pragma unroll
        for (int r = 0; r < 36; r += 2){
            float e0 = __expf(leaky(Sv[r * 85 + lc] * rnb[wave * 36 + r]));
            float e1 = __expf(leaky(Sv[(r + 1) * 85 + lc] * rnb[wave * 36 + r + 1]));
            num = fmaf(e0, Sv[r * 85 + 40], fmaf(e1, Sv[(r + 1) * 85 + 40], num));
            uh[r >> 1] = __builtin_amdgcn_cvt_pkrtz(e0, e1);
        }
        float zz = 0.f;
        #pragma unroll
        for (int rr = 0; rr < 36; ++rr){
            float w = 0.f;
            #pragma unroll
            for (int j = 0; j < 18; ++j)
                w = dot2h(uh[j], Gp[rr * 18 + j], w);
            zz = fmaf((float)uh[rr >> 1][rr & 1], w, zz);
        }
        float w2s = sqrtf(fmaxf(zz, 0.f));
        float sim = num / fmaxf(w1t[ig] * w2s, 1e-8f);   // dd cancels in ratio
        sim = (lane < 40) ? sim : 0.f;
        #pragma unroll
        for (int off = 32; off > 0; off >>= 1) sim += __shfl_down(sim, off);
        t2i_sum = sim;
    }

    {   // column norms over regions (lanes = words); 9x folded
        int l0 = (lane < 40) ? lane : 39;
        float s2 = 0.f;
        #pragma unroll
        for (int r = 0; r < 36; ++r){ float x = leaky(Sv[r * 85 + l0]); s2 = fmaf(x, x, s2); }
        if (lane < 40) cnb[wave * 40 + lane] = 9.f / (sqrtf(s2) + 1e-8f);
    }
    float i2t_sum;
    {   // lanes = regions; v packed as 20 f16 pairs
        int rc = (lane < 36) ? lane : 35;
        h16x2 vh[20];
        float num = 0.f;
        #pragma unroll
        for (int l = 0; l < 40; l += 2){
            float e0 = __expf(leaky(Sv[rc * 85 + l] * cnb[wave * 40 + l]));
            float e1 = __expf(leaky(Sv[rc * 85 + l + 1] * cnb[wave * 40 + l + 1]));
            num = fmaf(e0, Sv[36 * 85 + l], fmaf(e1, Sv[36 * 85 + l + 1], num));
            vh[l >> 1] = __builtin_amdgcn_cvt_pkrtz(e0, e1);
        }
        float zz = 0.f;
        #pragma unroll
        for (int ll = 0; ll < 40; ++ll){
            float w = 0.f;
            #pragma unroll
            for (int j = 0; j < 20; ++j)
                w = dot2h(vh[j], Hp[ll * 20 + j], w);
            zz = fmaf((float)vh[ll >> 1][ll & 1], w, zz);
        }
        float w2s = sqrtf(fmaxf(zz, 0.f));
        float sim = num / fmaxf(w1i[bg] * w2s, 1e-8f);
        sim = (lane < 36) ? sim : 0.f;
        #pragma unroll
        for (int off = 32; off > 0; off >>= 1) sim += __shfl_down(sim, off);
        i2t_sum = sim;
    }

    if (lane == 0)
        out[bg * 256 + ig] = t2i_sum * (1.f / 40.f) + i2t_sum * (1.f / 36.f) + Sv[36 * 85 + 40];
}

// ---------------------------------------------------------------------------
extern "C" void kernel_launch(void* const* d_in, const int* in_sizes, int n_in,
                              void* d_out, int out_size, void* d_ws, size_t ws_size,
                              hipStream_t stream){
    const float* pool_img = (const float*)d_in[0];
    const float* img_emb  = (const float*)d_in[1];
    const float* pool_txt = (const float*)d_in[2];
    const float* cap_emb  = (const float*)d_in[3];
    float* out = (float*)d_out;

    char* ws = (char*)d_ws;                         // needs ~41 MB
    size_t o = 0;
    u16* imgw = (u16*)(ws + o);  o += (size_t)256 * 37 * 1024 * 2;
    u16* capw = (u16*)(ws + o);  o += (size_t)256 * 41 * 1024 * 2;
    float* w1i = (float*)(ws + o); o += 1024;
    float* w1t = (float*)(ws + o); o += 1024;
    h16x2* Gh = (h16x2*)(ws + o); o += (size_t)256 * 648 * 4;   // G as f16 pairs
    h16x2* Hh = (h16x2*)(ws + o); o += (size_t)256 * 800 * 4;   // H as f16 pairs

    pack_kernel<<<19968, 256, 0, stream>>>(pool_img, img_emb, pool_txt, cap_emb,
                                           imgw, capw, w1i, w1t);
    gram_kernel<<<512, 256, 0, stream>>>(imgw, capw, Gh, Hh);
    fused_kernel<<<16384, 256, 0, stream>>>(imgw, capw, Gh, Hh, w1i, w1t, out);
}